// Round 10
// baseline (209.837 us; speedup 1.0000x reference)
//
#include <hip/hip_runtime.h>

// Attention block: B=8, C=D=128, H=W=64, N=4096.
// out = x + Wo·(softmax(Qᵀ K /√C) @ V) + bo, Q/K/V = 1x1-conv projections.
//
// attn: 32x32x16 MFMA, S = K·Q -> D[j][q]; j-order permuted so exp2(S) regs ARE
// the PV B-operand (V staged col-permuted in LDS). K is NOT staged: kt is stored
// pre-swizzled/blocked [b][jblk][c16][j64][e8] so S-phase A-frags are perfectly
// coalesced 1KB global loads (L1 serves the 4-wave reuse; barriers keep waves in
// lockstep). LDS traffic per wave-iter: 40KB -> 20KB (was LDS-pipe-bound).
// __launch_bounds__(256,2): acc AGPRs count against the unified file (round-8).
// Split-j x2; raw-O + l partials combined in outp.

typedef float  f32x4  __attribute__((ext_vector_type(4)));
typedef float  f32x16 __attribute__((ext_vector_type(16)));
typedef short  s16x8  __attribute__((ext_vector_type(8)));
typedef short  s16x4  __attribute__((ext_vector_type(4)));
typedef unsigned uint4v __attribute__((ext_vector_type(4)));

#define MFMA16(A, Bb, Cc) __builtin_amdgcn_mfma_f32_16x16x32_bf16(A, Bb, Cc, 0, 0, 0)
#define MFMA32(A, Bb, Cc) __builtin_amdgcn_mfma_f32_32x32x16_bf16(A, Bb, Cc, 0, 0, 0)

#define BATCH 8
#define DIM   128
#define NN    4096
#define NSPLIT 2
#define JCHUNK (NN / NSPLIT)
// 1/sqrt(128) * log2(e)  (q-scale so attn can use exp2)
#define Q_SCALE 0.12751649736784776f

__device__ __forceinline__ unsigned short f2bf(float f) {
  union { float f; unsigned u; } v; v.f = f;
  unsigned r = v.u + 0x7FFFu + ((v.u >> 16) & 1u);  // RNE
  return (unsigned short)(r >> 16);
}
__device__ __forceinline__ float bf2f(unsigned short h) {
  union { unsigned u; float f; } v; v.u = ((unsigned)h) << 16;
  return v.f;
}
__device__ __forceinline__ s16x8 cvt8(const float* src) {
  float4 a = *(const float4*)src;
  float4 b = *(const float4*)(src + 4);
  s16x8 f;
  f[0] = (short)f2bf(a.x); f[1] = (short)f2bf(a.y);
  f[2] = (short)f2bf(a.z); f[3] = (short)f2bf(a.w);
  f[4] = (short)f2bf(b.x); f[5] = (short)f2bf(b.y);
  f[6] = (short)f2bf(b.z); f[7] = (short)f2bf(b.w);
  return f;
}

// ---------------------------------------------------------------- QKV projection
// Grid (64 i-tiles, 8 batches). Block 256; each wave 16 i, 128 d, all 3 heads.
// x staged [c][i] fp32 pad 68; weights converted+staged per-z in padded LDS.
// K written in blocked layout [b][iblk][c][j][e] for attn's direct global frags.
__global__ __launch_bounds__(256) void qkv_kernel(
    const float* __restrict__ x,
    const float* __restrict__ wq, const float* __restrict__ wk,
    const float* __restrict__ wv,
    const float* __restrict__ bq, const float* __restrict__ bk,
    const float* __restrict__ bv,
    unsigned short* __restrict__ qt,          // [B][N][D]
    unsigned short* __restrict__ kt,          // blocked [B][64][16][64][8]
    unsigned short* __restrict__ vv) {        // [B][D][N]
  __shared__ float xs[DIM * 68];              // 34.8 KB
  __shared__ unsigned short wls[DIM * 136];   // 34.8 KB (one z at a time)
  const int b = blockIdx.y;
  const int i0 = blockIdx.x * 64;
  const int tid = threadIdx.x;

  for (int idx = tid; idx < 2048; idx += 256) {
    int c = idx >> 4, i4 = idx & 15;
    float4 val = *(const float4*)(x + ((size_t)(b * DIM + c)) * NN + i0 + i4 * 4);
    xs[c * 68 + i4 * 4 + 0] = val.x;
    xs[c * 68 + i4 * 4 + 1] = val.y;
    xs[c * 68 + i4 * 4 + 2] = val.z;
    xs[c * 68 + i4 * 4 + 3] = val.w;
  }
  __syncthreads();

  const int w = tid >> 6, lane = tid & 63, quad = lane >> 4, l15 = lane & 15;
  const int iloc = w * 16 + l15;

  // B-frags from x tile (once, reused by all 3 heads)
  s16x8 bfrag[4];
#pragma unroll
  for (int ch = 0; ch < 4; ch++) {
    s16x8 f;
#pragma unroll
    for (int jj = 0; jj < 8; jj++) {
      int c = ch * 32 + quad * 8 + jj;
      f[jj] = (short)f2bf(xs[c * 68 + iloc]);
    }
    bfrag[ch] = f;
  }

  const int i = i0 + iloc;
  const int wr = tid >> 4, wc = tid & 15;   // weight staging coords
  // blocked-K tile base for this (b, iblk): iblk == blockIdx.x
  unsigned short* ktb = kt + ((size_t)b * 64 + blockIdx.x) * 16384;

  for (int z = 0; z < 3; z++) {
    __syncthreads();  // prior z's wls reads done
    const float* wsrc = (z == 0) ? wq : (z == 1) ? wk : wv;
#pragma unroll
    for (int it = 0; it < 8; it++) {
      const int row = it * 16 + wr;
      *(s16x8*)(&wls[row * 136 + wc * 8]) = cvt8(wsrc + row * DIM + wc * 8);
    }
    __syncthreads();

    const float* bias = (z == 0) ? bq : (z == 1) ? bk : bv;
    const float sc = (z == 0) ? Q_SCALE : 1.0f;

    for (int t = 0; t < 8; t++) {
      const int dl = t * 16;
      f32x4 acc = {0.f, 0.f, 0.f, 0.f};
#pragma unroll
      for (int ch = 0; ch < 4; ch++) {
        s16x8 af = *(const s16x8*)(&wls[(dl + l15) * 136 + ch * 32 + quad * 8]);
        acc = MFMA16(af, bfrag[ch], acc);
      }
      if (z == 0) {
        s16x4 o;
#pragma unroll
        for (int r = 0; r < 4; r++) {
          int d = dl + quad * 4 + r;
          o[r] = (short)f2bf((acc[r] + bias[d]) * sc);
        }
        *(s16x4*)(qt + ((size_t)b * NN + i) * DIM + dl + quad * 4) = o;
      } else if (z == 1) {
        s16x4 o;
#pragma unroll
        for (int r = 0; r < 4; r++) {
          int d = dl + quad * 4 + r;
          o[r] = (short)f2bf(acc[r] + bias[d]);
        }
        const int c = t * 2 + (quad >> 1);      // d-chunk
        const int e = (quad & 1) * 4;
        *(s16x4*)(ktb + ((size_t)c * 64 + iloc) * 8 + e) = o;
      } else {
#pragma unroll
        for (int r = 0; r < 4; r++) {
          int d = dl + quad * 4 + r;
          vv[((size_t)b * DIM + d) * NN + i] = f2bf(acc[r] + bias[d]);
        }
      }
    }
  }
}

// ---------------------------------------------------------------- flash attention
// Grid (32 q-tiles of 128, 8 batches, 2 j-splits). 4 waves x 32 queries.
__global__ __launch_bounds__(256, 2) void attn_kernel(
    const unsigned short* __restrict__ qt,
    const unsigned short* __restrict__ kt,   // blocked [B][64][16][64][8]
    const unsigned short* __restrict__ vv,
    unsigned short* __restrict__ o_part,   // [S][B][N][D] bf16, un-normalized
    float* __restrict__ l_part) {          // [S][B][N]
  __shared__ unsigned short sh[16384];     // V tile [0,8192); epilogue uses all 32 KB
  const int b = blockIdx.y;
  const int i0 = blockIdx.x * 128;
  const int split = blockIdx.z;
  const int jbase = split * JCHUNK;
  const int tid = threadIdx.x;
  const int w = tid >> 6, lane = tid & 63;
  const int l31 = lane & 31, h = lane >> 5;

  const unsigned short* vb = vv + (size_t)b * DIM * NN;
  // blocked-K: tile for (b, jblk); advances by 16384 shorts per 64-j iter
  const unsigned short* ktile = kt + ((size_t)b * 64 + (jbase >> 6)) * 16384;
  const int koff = (h * 64 + l31) * 8;     // lane offset within a (c,jt) slab

  // persistent Q B-frags: B[k=d][n=q], lane n=l31, k = 16*kc + 8*h + i
  s16x8 qfrag[8];
  {
    const unsigned short* qrow =
        qt + ((size_t)b * NN + i0 + w * 32 + l31) * DIM + h * 8;
#pragma unroll
    for (int kc = 0; kc < 8; kc++)
      qfrag[kc] = *(const s16x8*)(qrow + kc * 16);
  }

  f32x16 acc[4];
#pragma unroll
  for (int mt = 0; mt < 4; mt++)
#pragma unroll
    for (int e = 0; e < 16; e++) acc[mt][e] = 0.f;
  float l_acc = 0.f;

  // V staging coordinates (iter-invariant)
  const int vr = tid >> 3, vc = tid & 7;     // V: row vr + it*32, 8-col group vc
  const int vch0 = (vc & 1) ? (vc - 1) : vc; // V column permutation
  const int vch1 = (vc & 1) ? vc : (vc + 1);
  const int vpos = (vc & 1) * 4;

  s16x8 vpre[4];
#pragma unroll
  for (int it = 0; it < 4; it++)
    vpre[it] = *(const s16x8*)(vb + (size_t)(it * 32 + vr) * NN + jbase + vc * 8);

  for (int j0 = jbase; j0 < jbase + JCHUNK; j0 += 64) {
    __syncthreads();  // prior iter's LDS reads done
    // ---- write prefetched V tile to LDS (swizzled, col-permuted)
#pragma unroll
    for (int it = 0; it < 4; it++) {
      const int r2 = it * 32 + vr;
      union { s16x8 v8; s16x4 v4[2]; } sp; sp.v8 = vpre[it];
      *(s16x4*)(sh + (((r2 << 3) + (vch0 ^ (r2 & 7))) << 3) + vpos) = sp.v4[0];
      *(s16x4*)(sh + (((r2 << 3) + (vch1 ^ (r2 & 7))) << 3) + vpos) = sp.v4[1];
    }
    __syncthreads();  // tile ready

    // ---- prefetch next iter's V into registers (no barrier dependency)
    if (j0 + 64 < jbase + JCHUNK) {
      const int jn = j0 + 64;
#pragma unroll
      for (int it = 0; it < 4; it++)
        vpre[it] = *(const s16x8*)(vb + (size_t)(it * 32 + vr) * NN + jn + vc * 8);
    }

    // ---- S = K·Q -> D[j][q]; K A-frags DIRECT from blocked global layout
#pragma unroll
    for (int jt = 0; jt < 2; jt++) {
      f32x16 S;
#pragma unroll
      for (int e = 0; e < 16; e++) S[e] = 0.f;
#pragma unroll
      for (int kc = 0; kc < 8; kc++) {
        s16x8 kf = *(const s16x8*)(ktile + kc * 1024 + jt * 256 + koff);
        S = MFMA32(kf, qfrag[kc], S);
      }
      unsigned pk[8];
#pragma unroll
      for (int p = 0; p < 8; p++) {
        float e0 = exp2f(S[2 * p]), e1 = exp2f(S[2 * p + 1]);
        l_acc += e0 + e1;
        union { float f; unsigned u; } u0, u1; u0.f = e0; u1.f = e1;
        pk[p] = __builtin_amdgcn_perm(u1.u, u0.u, 0x07060302u);  // [bf16(e0),bf16(e1)]
      }
#pragma unroll
      for (int bl = 0; bl < 2; bl++) {
        union { uint4v u; s16x8 v; } pu;
        pu.u[0] = pk[4 * bl + 0]; pu.u[1] = pk[4 * bl + 1];
        pu.u[2] = pk[4 * bl + 2]; pu.u[3] = pk[4 * bl + 3];
        const s16x8 pf = pu.v;
        const int c0 = (jt * 2 + bl) * 2 + h;  // logical V chunk
#pragma unroll
        for (int mt = 0; mt < 4; mt++) {
          const int d = mt * 32 + l31;
          s16x8 vf = *(const s16x8*)(sh + (((d << 3) + (c0 ^ (d & 7))) << 3));
          acc[mt] = MFMA32(vf, pf, acc[mt]);
        }
      }
    }
    ktile += 16384;
  }

  const float l_tot = l_acc + __shfl_xor(l_acc, 32, 64);

  // ---- epilogue: transpose O via per-wave LDS slice, coalesced b128 stores
  __syncthreads();  // all waves done reading V tile
  unsigned short* ep = sh + w * 4096;  // 8 KB per wave
#pragma unroll
  for (int mt = 0; mt < 4; mt++)
#pragma unroll
    for (int reg = 0; reg < 16; reg++) {
      int d = mt * 32 + (reg & 3) + 8 * (reg >> 2) + 4 * h;
      int dc = d >> 3;
      ep[(l31 << 7) + ((dc ^ (l31 & 15)) << 3) + (d & 7)] = f2bf(acc[mt][reg]);
    }
  __syncthreads();
#pragma unroll
  for (int it = 0; it < 8; it++) {
    int qr = it * 4 + (lane >> 4), cr = lane & 15;
    s16x8 v = *(const s16x8*)(ep + (qr << 7) + ((cr ^ (qr & 15)) << 3));
    *(s16x8*)(o_part + (((size_t)split * BATCH + b) * NN + i0 + w * 32 + qr) * DIM +
              cr * 8) = v;
  }
  if (lane < 32)
    l_part[((size_t)split * BATCH + b) * NN + i0 + w * 32 + lane] = l_tot;
}

// ---------------------------------------------------------------- output projection
// Fused combine + Wo GEMM + residual. Grid (64 i-tiles of 64, 8 batches), block 256.
// Wo converted fp32->bf16 into padded LDS (A-frags via ds_read_b128).
__global__ __launch_bounds__(256) void outp_kernel(
    const float* __restrict__ x,
    const float* __restrict__ wo,
    const float* __restrict__ bo,
    const unsigned short* __restrict__ o_part,
    const float* __restrict__ l_part,
    float* __restrict__ out) {
  __shared__ unsigned short ytile[64 * 136];  // 17.4 KB
  __shared__ unsigned short wls[DIM * 136];   // 34.8 KB
  __shared__ float invl[64];
  const int b = blockIdx.y;
  const int i0 = blockIdx.x * 64;
  const int tid = threadIdx.x;
  const int wr = tid >> 4, wc = tid & 15;

  // stage Wo (fp32 -> bf16, padded LDS)
#pragma unroll
  for (int it = 0; it < 8; it++) {
    const int row = it * 16 + wr;
    *(s16x8*)(&wls[row * 136 + wc * 8]) = cvt8(wo + row * DIM + wc * 8);
  }

  if (tid < 64) {
    float l = 0.f;
#pragma unroll
    for (int s = 0; s < NSPLIT; s++)
      l += l_part[((size_t)s * BATCH + b) * NN + i0 + tid];
    invl[tid] = 1.0f / l;
  }
  __syncthreads();

  // Phase 1: coalesced row-major o_part reads; sum splits; normalize; LDS y-tile
#pragma unroll
  for (int k = 0; k < 4; k++) {
    int slot = k * 256 + tid;            // 1024 slots = 64 rows x 16 granules
    int i = slot >> 4, g = slot & 15;
    float o[8] = {0.f, 0.f, 0.f, 0.f, 0.f, 0.f, 0.f, 0.f};
#pragma unroll
    for (int s = 0; s < NSPLIT; s++) {
      s16x8 ov = *(const s16x8*)(o_part +
                                 (((size_t)s * BATCH + b) * NN + i0 + i) * DIM + g * 8);
#pragma unroll
      for (int jj = 0; jj < 8; jj++) o[jj] += bf2f((unsigned short)ov[jj]);
    }
    const float inv = invl[i];
    s16x8 f;
#pragma unroll
    for (int jj = 0; jj < 8; jj++) f[jj] = (short)f2bf(o[jj] * inv);
    *(s16x8*)(&ytile[i * 136 + g * 8]) = f;
  }
  __syncthreads();

  // Phase 2: Wo GEMM from LDS A- and B-frags + bias + residual
  const int w = tid >> 6, lane = tid & 63, quad = lane >> 4, l15 = lane & 15;
  const int i = i0 + w * 16 + l15;

  s16x8 bfrag[4];
#pragma unroll
  for (int ch = 0; ch < 4; ch++)
    bfrag[ch] = *(const s16x8*)(&ytile[(w * 16 + l15) * 136 + ch * 32 + quad * 8]);

  for (int t = 0; t < 8; t++) {
    f32x4 acc = {0.f, 0.f, 0.f, 0.f};
#pragma unroll
    for (int ch = 0; ch < 4; ch++) {
      s16x8 af = *(const s16x8*)(&wls[(t * 16 + l15) * 136 + ch * 32 + quad * 8]);
      acc = MFMA16(af, bfrag[ch], acc);
    }
#pragma unroll
    for (int r = 0; r < 4; r++) {
      int d = t * 16 + quad * 4 + r;
      size_t idx = ((size_t)b * DIM + d) * NN + i;
      out[idx] = x[idx] + acc[r] + bo[d];
    }
  }
}

// ---------------------------------------------------------------- launch
extern "C" void kernel_launch(void* const* d_in, const int* in_sizes, int n_in,
                              void* d_out, int out_size, void* d_ws, size_t ws_size,
                              hipStream_t stream) {
  const float* x  = (const float*)d_in[0];
  const float* wq = (const float*)d_in[1];
  const float* bq = (const float*)d_in[2];
  const float* wk = (const float*)d_in[3];
  const float* bk = (const float*)d_in[4];
  const float* wv = (const float*)d_in[5];
  const float* bv = (const float*)d_in[6];
  const float* wo = (const float*)d_in[7];
  const float* bo = (const float*)d_in[8];
  float* out = (float*)d_out;

  unsigned short* ws  = (unsigned short*)d_ws;
  unsigned short* qt  = ws;                                 // 8 MB
  unsigned short* kt  = qt + (size_t)BATCH * NN * DIM;      // 8 MB (blocked)
  unsigned short* vv  = kt + (size_t)BATCH * NN * DIM;      // 8 MB
  unsigned short* o_part = vv + (size_t)BATCH * NN * DIM;   // 16 MB (2 splits)
  float* l_part = (float*)(o_part + (size_t)NSPLIT * BATCH * NN * DIM);  // 256 KB

  hipLaunchKernelGGL(qkv_kernel, dim3(64, 8), dim3(256), 0, stream,
                     x, wq, wk, wv, bq, bk, bv, qt, kt, vv);
  hipLaunchKernelGGL(attn_kernel, dim3(32, 8, NSPLIT), dim3(256), 0, stream,
                     qt, kt, vv, o_part, l_part);
  hipLaunchKernelGGL(outp_kernel, dim3(64, 8), dim3(256), 0, stream,
                     x, wo, bo, o_part, l_part, out);
}

// Round 12
// 179.036 us; speedup vs baseline: 1.1720x; 1.1720x over previous
//
#include <hip/hip_runtime.h>

// Attention block: B=8, C=D=128, H=W=64, N=4096.
// out = x + Wo·(softmax(Qᵀ K /√C) @ V) + bo, Q/K/V = 1x1-conv projections.
//
// attn: 32x32x16 MFMA, S = K·Q -> D[j][q]; j-order permuted so exp2(S) regs ARE
// the PV B-operand (V staged col-permuted in LDS). K+V tiles in LDS (round-10
// direct-global-K regressed: ~200cy latency under the S-MFMA chain at 2 blk/CU).
// Split-j x2: grid = 512 blocks = exactly one co-resident cohort (2/CU); halves
// o_part traffic vs x4 and amortizes prologue/epilogue over 32 j-iters.
// __launch_bounds__(256,2): acc AGPRs count against the unified file (round-8:
// (256,3) -> VGPR cap 128 -> scratch spill).
// qkv: fused q/k/v; x staged once; weights fp32->bf16 inline into padded LDS.
// outp: combine 2 partials + Wo GEMM (Wo in padded LDS) + residual.
// Round-11: hipLaunchCooperativeKernel never executed (poison output) — 3
// normal launches it is.

typedef float  f32x4  __attribute__((ext_vector_type(4)));
typedef float  f32x16 __attribute__((ext_vector_type(16)));
typedef short  s16x8  __attribute__((ext_vector_type(8)));
typedef short  s16x4  __attribute__((ext_vector_type(4)));
typedef unsigned uint4v __attribute__((ext_vector_type(4)));

#define MFMA16(A, Bb, Cc) __builtin_amdgcn_mfma_f32_16x16x32_bf16(A, Bb, Cc, 0, 0, 0)
#define MFMA32(A, Bb, Cc) __builtin_amdgcn_mfma_f32_32x32x16_bf16(A, Bb, Cc, 0, 0, 0)

#define BATCH 8
#define DIM   128
#define NN    4096
#define NSPLIT 2
#define JCHUNK (NN / NSPLIT)
// 1/sqrt(128) * log2(e)  (q-scale so attn can use exp2)
#define Q_SCALE 0.12751649736784776f

__device__ __forceinline__ unsigned short f2bf(float f) {
  union { float f; unsigned u; } v; v.f = f;
  unsigned r = v.u + 0x7FFFu + ((v.u >> 16) & 1u);  // RNE
  return (unsigned short)(r >> 16);
}
__device__ __forceinline__ float bf2f(unsigned short h) {
  union { unsigned u; float f; } v; v.u = ((unsigned)h) << 16;
  return v.f;
}
__device__ __forceinline__ s16x8 cvt8(const float* src) {
  float4 a = *(const float4*)src;
  float4 b = *(const float4*)(src + 4);
  s16x8 f;
  f[0] = (short)f2bf(a.x); f[1] = (short)f2bf(a.y);
  f[2] = (short)f2bf(a.z); f[3] = (short)f2bf(a.w);
  f[4] = (short)f2bf(b.x); f[5] = (short)f2bf(b.y);
  f[6] = (short)f2bf(b.z); f[7] = (short)f2bf(b.w);
  return f;
}

// ---------------------------------------------------------------- QKV projection
// Grid (64 i-tiles, 8 batches). Block 256; each wave 16 i, 128 d, all 3 heads.
// x staged [c][i] fp32 pad 68; weights converted+staged per-z in padded LDS.
__global__ __launch_bounds__(256) void qkv_kernel(
    const float* __restrict__ x,
    const float* __restrict__ wq, const float* __restrict__ wk,
    const float* __restrict__ wv,
    const float* __restrict__ bq, const float* __restrict__ bk,
    const float* __restrict__ bv,
    unsigned short* __restrict__ qt,          // [B][N][D]
    unsigned short* __restrict__ kt,          // [B][N][D]
    unsigned short* __restrict__ vv) {        // [B][D][N]
  __shared__ float xs[DIM * 68];              // 34.8 KB
  __shared__ unsigned short wls[DIM * 136];   // 34.8 KB (one z at a time)
  const int b = blockIdx.y;
  const int i0 = blockIdx.x * 64;
  const int tid = threadIdx.x;

  for (int idx = tid; idx < 2048; idx += 256) {
    int c = idx >> 4, i4 = idx & 15;
    float4 val = *(const float4*)(x + ((size_t)(b * DIM + c)) * NN + i0 + i4 * 4);
    xs[c * 68 + i4 * 4 + 0] = val.x;
    xs[c * 68 + i4 * 4 + 1] = val.y;
    xs[c * 68 + i4 * 4 + 2] = val.z;
    xs[c * 68 + i4 * 4 + 3] = val.w;
  }
  __syncthreads();

  const int w = tid >> 6, lane = tid & 63, quad = lane >> 4, l15 = lane & 15;
  const int iloc = w * 16 + l15;

  // B-frags from x tile (once, reused by all 3 heads)
  s16x8 bfrag[4];
#pragma unroll
  for (int ch = 0; ch < 4; ch++) {
    s16x8 f;
#pragma unroll
    for (int jj = 0; jj < 8; jj++) {
      int c = ch * 32 + quad * 8 + jj;
      f[jj] = (short)f2bf(xs[c * 68 + iloc]);
    }
    bfrag[ch] = f;
  }

  const int i = i0 + iloc;
  const int wr = tid >> 4, wc = tid & 15;   // weight staging coords

  for (int z = 0; z < 3; z++) {
    __syncthreads();  // prior z's wls reads done
    const float* wsrc = (z == 0) ? wq : (z == 1) ? wk : wv;
#pragma unroll
    for (int it = 0; it < 8; it++) {
      const int row = it * 16 + wr;
      *(s16x8*)(&wls[row * 136 + wc * 8]) = cvt8(wsrc + row * DIM + wc * 8);
    }
    __syncthreads();

    const float* bias = (z == 0) ? bq : (z == 1) ? bk : bv;
    const float sc = (z == 0) ? Q_SCALE : 1.0f;

    for (int t = 0; t < 8; t++) {
      const int dl = t * 16;
      f32x4 acc = {0.f, 0.f, 0.f, 0.f};
#pragma unroll
      for (int ch = 0; ch < 4; ch++) {
        s16x8 af = *(const s16x8*)(&wls[(dl + l15) * 136 + ch * 32 + quad * 8]);
        acc = MFMA16(af, bfrag[ch], acc);
      }
      if (z < 2) {
        unsigned short* dstb = (z == 0) ? qt : kt;
        s16x4 o;
#pragma unroll
        for (int r = 0; r < 4; r++) {
          int d = dl + quad * 4 + r;
          o[r] = (short)f2bf((acc[r] + bias[d]) * sc);
        }
        *(s16x4*)(dstb + ((size_t)b * NN + i) * DIM + dl + quad * 4) = o;
      } else {
#pragma unroll
        for (int r = 0; r < 4; r++) {
          int d = dl + quad * 4 + r;
          vv[((size_t)b * DIM + d) * NN + i] = f2bf(acc[r] + bias[d]);
        }
      }
    }
  }
}

// ---------------------------------------------------------------- flash attention
// Grid (32 q-tiles of 128, 8 batches, 2 j-splits) = 512 blocks. 4 waves x 32 q.
__global__ __launch_bounds__(256, 2) void attn_kernel(
    const unsigned short* __restrict__ qt,
    const unsigned short* __restrict__ kt,
    const unsigned short* __restrict__ vv,
    unsigned short* __restrict__ o_part,   // [S][B][N][D] bf16, un-normalized
    float* __restrict__ l_part) {          // [S][B][N]
  __shared__ unsigned short sh[16384];     // 32 KB: K [0,8192), V [8192,16384)
  const int b = blockIdx.y;
  const int i0 = blockIdx.x * 128;
  const int split = blockIdx.z;
  const int jbase = split * JCHUNK;
  const int tid = threadIdx.x;
  const int w = tid >> 6, lane = tid & 63;
  const int l31 = lane & 31, h = lane >> 5;

  const unsigned short* kb = kt + (size_t)b * NN * DIM;
  const unsigned short* vb = vv + (size_t)b * DIM * NN;

  // persistent Q B-frags: B[k=d][n=q], lane n=l31, k = 16*kc + 8*h + i
  s16x8 qfrag[8];
  {
    const unsigned short* qrow =
        qt + ((size_t)b * NN + i0 + w * 32 + l31) * DIM + h * 8;
#pragma unroll
    for (int kc = 0; kc < 8; kc++)
      qfrag[kc] = *(const s16x8*)(qrow + kc * 16);
  }

  f32x16 acc[4];
#pragma unroll
  for (int mt = 0; mt < 4; mt++)
#pragma unroll
    for (int e = 0; e < 16; e++) acc[mt][e] = 0.f;
  float l_acc = 0.f;

  // staging thread coordinates (iter-invariant)
  const int kr = tid >> 4, kc_ = tid & 15;   // K: row kr + it*16, chunk kc_
  const int vr = tid >> 3, vc = tid & 7;     // V: row vr + it*32, 8-col group vc
  const int vch0 = (vc & 1) ? (vc - 1) : vc; // V column permutation
  const int vch1 = (vc & 1) ? vc : (vc + 1);
  const int vpos = (vc & 1) * 4;

  s16x8 kpre[4], vpre[4];
#pragma unroll
  for (int it = 0; it < 4; it++) {
    kpre[it] = *(const s16x8*)(kb + (size_t)(jbase + it * 16 + kr) * DIM + kc_ * 8);
    vpre[it] = *(const s16x8*)(vb + (size_t)(it * 32 + vr) * NN + jbase + vc * 8);
  }

  for (int j0 = jbase; j0 < jbase + JCHUNK; j0 += 64) {
    __syncthreads();  // prior iter's LDS reads done
    // ---- write prefetched K/V tiles to LDS (swizzled; V col-permuted)
#pragma unroll
    for (int it = 0; it < 4; it++) {
      const int r = it * 16 + kr;
      *(s16x8*)(sh + (((r << 4) + (kc_ ^ (r & 15))) << 3)) = kpre[it];
      const int r2 = it * 32 + vr;
      union { s16x8 v8; s16x4 v4[2]; } sp; sp.v8 = vpre[it];
      *(s16x4*)(sh + 8192 + (((r2 << 3) + (vch0 ^ (r2 & 7))) << 3) + vpos) = sp.v4[0];
      *(s16x4*)(sh + 8192 + (((r2 << 3) + (vch1 ^ (r2 & 7))) << 3) + vpos) = sp.v4[1];
    }
    __syncthreads();  // tiles ready

    // ---- prefetch next iter's tiles into registers (no barrier dependency)
    if (j0 + 64 < jbase + JCHUNK) {
      const int jn = j0 + 64;
#pragma unroll
      for (int it = 0; it < 4; it++) {
        kpre[it] = *(const s16x8*)(kb + (size_t)(jn + it * 16 + kr) * DIM + kc_ * 8);
        vpre[it] = *(const s16x8*)(vb + (size_t)(it * 32 + vr) * NN + jn + vc * 8);
      }
    }

    // ---- S = K·Q -> D[j][q]; P = exp2(S); PV straight from S registers
#pragma unroll
    for (int jt = 0; jt < 2; jt++) {
      f32x16 S;
#pragma unroll
      for (int e = 0; e < 16; e++) S[e] = 0.f;
      const int j = jt * 32 + l31;
#pragma unroll
      for (int kc = 0; kc < 8; kc++) {
        s16x8 kf = *(const s16x8*)(sh + (((j << 4) + ((2 * kc + h) ^ (j & 15))) << 3));
        S = MFMA32(kf, qfrag[kc], S);
      }
      unsigned pk[8];
#pragma unroll
      for (int p = 0; p < 8; p++) {
        float e0 = exp2f(S[2 * p]), e1 = exp2f(S[2 * p + 1]);
        l_acc += e0 + e1;
        union { float f; unsigned u; } u0, u1; u0.f = e0; u1.f = e1;
        pk[p] = __builtin_amdgcn_perm(u1.u, u0.u, 0x07060302u);  // [bf16(e0),bf16(e1)]
      }
#pragma unroll
      for (int bl = 0; bl < 2; bl++) {
        union { uint4v u; s16x8 v; } pu;
        pu.u[0] = pk[4 * bl + 0]; pu.u[1] = pk[4 * bl + 1];
        pu.u[2] = pk[4 * bl + 2]; pu.u[3] = pk[4 * bl + 3];
        const s16x8 pf = pu.v;
        const int c0 = (jt * 2 + bl) * 2 + h;  // logical V chunk
#pragma unroll
        for (int mt = 0; mt < 4; mt++) {
          const int d = mt * 32 + l31;
          s16x8 vf = *(const s16x8*)(sh + 8192 + (((d << 3) + (c0 ^ (d & 7))) << 3));
          acc[mt] = MFMA32(vf, pf, acc[mt]);
        }
      }
    }
  }

  const float l_tot = l_acc + __shfl_xor(l_acc, 32, 64);

  // ---- epilogue: transpose O via per-wave LDS slice, coalesced b128 stores
  __syncthreads();  // all waves done reading K/V tiles
  unsigned short* ep = sh + w * 4096;  // 8 KB per wave
#pragma unroll
  for (int mt = 0; mt < 4; mt++)
#pragma unroll
    for (int reg = 0; reg < 16; reg++) {
      int d = mt * 32 + (reg & 3) + 8 * (reg >> 2) + 4 * h;
      int dc = d >> 3;
      ep[(l31 << 7) + ((dc ^ (l31 & 15)) << 3) + (d & 7)] = f2bf(acc[mt][reg]);
    }
  __syncthreads();
#pragma unroll
  for (int it = 0; it < 8; it++) {
    int qr = it * 4 + (lane >> 4), cr = lane & 15;
    s16x8 v = *(const s16x8*)(ep + (qr << 7) + ((cr ^ (qr & 15)) << 3));
    *(s16x8*)(o_part + (((size_t)split * BATCH + b) * NN + i0 + w * 32 + qr) * DIM +
              cr * 8) = v;
  }
  if (lane < 32)
    l_part[((size_t)split * BATCH + b) * NN + i0 + w * 32 + lane] = l_tot;
}

// ---------------------------------------------------------------- output projection
// Fused combine + Wo GEMM + residual. Grid (64 i-tiles of 64, 8 batches), block 256.
// Wo converted fp32->bf16 into padded LDS (A-frags via ds_read_b128).
__global__ __launch_bounds__(256) void outp_kernel(
    const float* __restrict__ x,
    const float* __restrict__ wo,
    const float* __restrict__ bo,
    const unsigned short* __restrict__ o_part,
    const float* __restrict__ l_part,
    float* __restrict__ out) {
  __shared__ unsigned short ytile[64 * 136];  // 17.4 KB
  __shared__ unsigned short wls[DIM * 136];   // 34.8 KB
  __shared__ float invl[64];
  const int b = blockIdx.y;
  const int i0 = blockIdx.x * 64;
  const int tid = threadIdx.x;
  const int wr = tid >> 4, wc = tid & 15;

  // stage Wo (fp32 -> bf16, padded LDS)
#pragma unroll
  for (int it = 0; it < 8; it++) {
    const int row = it * 16 + wr;
    *(s16x8*)(&wls[row * 136 + wc * 8]) = cvt8(wo + row * DIM + wc * 8);
  }

  if (tid < 64) {
    float l = 0.f;
#pragma unroll
    for (int s = 0; s < NSPLIT; s++)
      l += l_part[((size_t)s * BATCH + b) * NN + i0 + tid];
    invl[tid] = 1.0f / l;
  }
  __syncthreads();

  // Phase 1: coalesced row-major o_part reads; sum splits; normalize; LDS y-tile
#pragma unroll
  for (int k = 0; k < 4; k++) {
    int slot = k * 256 + tid;            // 1024 slots = 64 rows x 16 granules
    int i = slot >> 4, g = slot & 15;
    float o[8] = {0.f, 0.f, 0.f, 0.f, 0.f, 0.f, 0.f, 0.f};
#pragma unroll
    for (int s = 0; s < NSPLIT; s++) {
      s16x8 ov = *(const s16x8*)(o_part +
                                 (((size_t)s * BATCH + b) * NN + i0 + i) * DIM + g * 8);
#pragma unroll
      for (int jj = 0; jj < 8; jj++) o[jj] += bf2f((unsigned short)ov[jj]);
    }
    const float inv = invl[i];
    s16x8 f;
#pragma unroll
    for (int jj = 0; jj < 8; jj++) f[jj] = (short)f2bf(o[jj] * inv);
    *(s16x8*)(&ytile[i * 136 + g * 8]) = f;
  }
  __syncthreads();

  // Phase 2: Wo GEMM from LDS A- and B-frags + bias + residual
  const int w = tid >> 6, lane = tid & 63, quad = lane >> 4, l15 = lane & 15;
  const int i = i0 + w * 16 + l15;

  s16x8 bfrag[4];
#pragma unroll
  for (int ch = 0; ch < 4; ch++)
    bfrag[ch] = *(const s16x8*)(&ytile[(w * 16 + l15) * 136 + ch * 32 + quad * 8]);

  for (int t = 0; t < 8; t++) {
    f32x4 acc = {0.f, 0.f, 0.f, 0.f};
#pragma unroll
    for (int ch = 0; ch < 4; ch++) {
      s16x8 af = *(const s16x8*)(&wls[(t * 16 + l15) * 136 + ch * 32 + quad * 8]);
      acc = MFMA16(af, bfrag[ch], acc);
    }
#pragma unroll
    for (int r = 0; r < 4; r++) {
      int d = t * 16 + quad * 4 + r;
      size_t idx = ((size_t)b * DIM + d) * NN + i;
      out[idx] = x[idx] + acc[r] + bo[d];
    }
  }
}

// ---------------------------------------------------------------- launch
extern "C" void kernel_launch(void* const* d_in, const int* in_sizes, int n_in,
                              void* d_out, int out_size, void* d_ws, size_t ws_size,
                              hipStream_t stream) {
  const float* x  = (const float*)d_in[0];
  const float* wq = (const float*)d_in[1];
  const float* bq = (const float*)d_in[2];
  const float* wk = (const float*)d_in[3];
  const float* bk = (const float*)d_in[4];
  const float* wv = (const float*)d_in[5];
  const float* bv = (const float*)d_in[6];
  const float* wo = (const float*)d_in[7];
  const float* bo = (const float*)d_in[8];
  float* out = (float*)d_out;

  unsigned short* ws  = (unsigned short*)d_ws;
  unsigned short* qt  = ws;                                 // 8 MB
  unsigned short* kt  = qt + (size_t)BATCH * NN * DIM;      // 8 MB
  unsigned short* vv  = kt + (size_t)BATCH * NN * DIM;      // 8 MB
  unsigned short* o_part = vv + (size_t)BATCH * NN * DIM;   // 16 MB (2 splits)
  float* l_part = (float*)(o_part + (size_t)NSPLIT * BATCH * NN * DIM);  // 256 KB

  hipLaunchKernelGGL(qkv_kernel, dim3(64, 8), dim3(256), 0, stream,
                     x, wq, wk, wv, bq, bk, bv, qt, kt, vv);
  hipLaunchKernelGGL(attn_kernel, dim3(32, 8, NSPLIT), dim3(256), 0, stream,
                     qt, kt, vv, o_part, l_part);
  hipLaunchKernelGGL(outp_kernel, dim3(64, 8), dim3(256), 0, stream,
                     x, wo, bo, o_part, l_part, out);
}